// Round 2
// baseline (456.716 us; speedup 1.0000x reference)
//
#include <hip/hip_runtime.h>
#include <stdint.h>
#include <math.h>

#define NW 741
#define NEG_INF_KEY 0x007FFFFFu  // key(-inf)

// Bit-exact chained row-major fp32 window sum, then fp32 divide by H*W.
// Matches naive reduce_window lowering (and a naive numpy float32 port).
template<int H, int W, int OFF>
__device__ __forceinline__ void score_ratio(const float* __restrict__ im,
                                            float* __restrict__ wk,
                                            float* __restrict__ wrow,
                                            const int lane) {
  constexpr int Wo = 14 - W + 1;
  constexpr int Ho = 14 - H + 1;
  constexpr int NWIN = Ho * Wo;
  for (int o = lane; o < NWIN; o += 64) {
    const int i = o / Wo, j = o - i * Wo;
    const float* p = im + i * 14 + j;
    float acc = 0.0f;
#pragma unroll
    for (int di = 0; di < H; ++di)
#pragma unroll
      for (int dj = 0; dj < W; ++dj)
        acc += p[di * 14 + dj];
    const float sc = acc / (float)(H * W);   // IEEE fp32 div (no fast-math)
    wk[OFF + o] = sc;
    wrow[OFF + o] = sc;
  }
}

__global__ __launch_bounds__(256) void appm_kernel(
    const float* __restrict__ x, const int* __restrict__ coords,
    float* __restrict__ out, int B) {

  __shared__ float c_x0[NW], c_y0[NW], c_x1[NW], c_y1[NW], c_area[NW];
  __shared__ float img[4][196];
  __shared__ float work[4][NW];

  const int t = threadIdx.x;
  const int wv = t >> 6;
  const int lane = t & 63;
  const int img0 = blockIdx.x * 4;
  const int imgi = img0 + wv;
  const bool active = (imgi < B);

  // ---- Phase A: coord tables (float coords + areas), shared per block ----
  for (int widx = t; widx < NW; widx += 256) {
    const int4 c = ((const int4*)coords)[widx];
    const float fx0 = (float)c.x, fy0 = (float)c.y;
    const float fx1 = (float)c.z, fy1 = (float)c.w;
    c_x0[widx] = fx0; c_y0[widx] = fy0; c_x1[widx] = fx1; c_y1[widx] = fy1;
    c_area[widx] = (fx1 - fx0 + 1.0f) * (fy1 - fy0 + 1.0f);
  }

  // ---- Phase B: stage 4 images (784 contiguous floats) into LDS ----
  {
    int lim = (B - img0) * 196;
    if (lim > 784) lim = 784;
    const float* xb = x + (long long)img0 * 196;
    for (int u = t; u < lim; u += 256) ((float*)img)[u] = xb[u];
  }
  __syncthreads();

  // ---- Phase C: 741 window scores, bit-exact fp32, ratio-major ----
  float* wk = work[wv];
  const float* im = img[wv];
  if (active) {
    float* wrow = out + (long long)B * 12 + (long long)imgi * NW;
    score_ratio<4, 4, 0>(im, wk, wrow, lane);
    score_ratio<3, 5, 121>(im, wk, wrow, lane);
    score_ratio<5, 3, 241>(im, wk, wrow, lane);
    score_ratio<6, 6, 361>(im, wk, wrow, lane);
    score_ratio<5, 7, 442>(im, wk, wrow, lane);
    score_ratio<7, 5, 522>(im, wk, wrow, lane);
    score_ratio<8, 8, 602>(im, wk, wrow, lane);
    score_ratio<6, 10, 651>(im, wk, wrow, lane);
    score_ratio<10, 6, 696>(im, wk, wrow, lane);
  }
  __syncthreads();

  // ---- Phase D: per-wave greedy NMS, 3 groups ----
  if (active) {
    float my_idx_f = 0.0f, my_score = 0.0f;
    int pick = 0;
    constexpr int gs_[3] = {0, 361, 602};
    constexpr int ge_[3] = {361, 602, 741};
    constexpr int gn_[3] = {3, 2, 1};
#pragma unroll
    for (int g = 0; g < 3; g++) {
      int last = gs_[g];
      float last_sc = 0.0f;
#pragma unroll
      for (int n = 0; n < gn_[g]; n++) {
        // local argmax over this lane's strided windows (monotone uint key)
        unsigned bkey = 0u;
        int bidx = 0;
        for (int o = gs_[g] + lane; o < ge_[g]; o += 64) {
          const unsigned u = __float_as_uint(wk[o]);
          const unsigned key = (u & 0x80000000u) ? ~u : (u | 0x80000000u);
          if (key > bkey) { bkey = key; bidx = o; }
        }
        // wave-wide argmax butterfly (ties -> lowest index, matches jnp.argmax)
#pragma unroll
        for (int dsh = 1; dsh < 64; dsh <<= 1) {
          const unsigned okey = (unsigned)__shfl_xor((int)bkey, dsh, 64);
          const int oidx = __shfl_xor(bidx, dsh, 64);
          if (okey > bkey || (okey == bkey && oidx < bidx)) { bkey = okey; bidx = oidx; }
        }
        const bool found = (bkey > NEG_INF_KEY);
        int idx; float sc;
        if (found) {
          idx = bidx;
          const unsigned u = (bkey & 0x80000000u) ? (bkey ^ 0x80000000u) : ~bkey;
          sc = __uint_as_float(u);
        } else {
          idx = last; sc = last_sc;
        }
        last = idx; last_sc = sc;
        if (lane == pick) { my_idx_f = (float)idx; my_score = sc; }
        pick++;

        if (n + 1 < gn_[g]) {   // suppression (skip after final pick of group)
          const float cx0 = c_x0[idx], cy0 = c_y0[idx];
          const float cx1 = c_x1[idx], cy1 = c_y1[idx];
          const float car = c_area[idx];
          for (int o = gs_[g] + lane; o < ge_[g]; o += 64) {
            const float lx = fminf(c_x1[o], cx1) - fmaxf(c_x0[o], cx0) + 1.0f;
            const float ly = fminf(c_y1[o], cy1) - fmaxf(c_y0[o], cy0) + 1.0f;
            const float inter = (lx < 0.0f || ly < 0.0f) ? 0.0f : lx * ly;
            const float iou = inter / (c_area[o] + car - inter);
            if (iou > 0.25f) wk[o] = -INFINITY;
          }
          __builtin_amdgcn_wave_barrier();
        }
      }
    }
    // ---- outputs: indices (as float) and chosen scores ----
    if (lane < 6) {
      const long long b6 = (long long)imgi * 6 + lane;
      out[b6] = my_idx_f;
      out[(long long)B * 6 + b6] = my_score;
    }
  }
}

extern "C" void kernel_launch(void* const* d_in, const int* in_sizes, int n_in,
                              void* d_out, int out_size, void* d_ws, size_t ws_size,
                              hipStream_t stream) {
  const float* x = (const float*)d_in[0];
  const int* coords = (const int*)d_in[1];
  float* out = (float*)d_out;
  const int B = in_sizes[0] / 196;
  const int nblk = (B + 3) / 4;
  appm_kernel<<<dim3(nblk), dim3(256), 0, stream>>>(x, coords, out, B);
}

// Round 3
// 443.442 us; speedup vs baseline: 1.0299x; 1.0299x over previous
//
#include <hip/hip_runtime.h>
#include <stdint.h>
#include <math.h>

#define NW 741
#define NEG_INF_KEY 0x007FFFFFu  // key(-inf); real finite scores map strictly above

__device__ __forceinline__ unsigned score_key(float f) {
  const unsigned u = __float_as_uint(f);
  return (u & 0x80000000u) ? ~u : (u | 0x80000000u);
}
__device__ __forceinline__ float key_score(unsigned k) {
  return __uint_as_float((k & 0x80000000u) ? (k ^ 0x80000000u) : ~k);
}

// 6-step DPP argmax over the 64-lane wave (tie -> lowest index), result
// broadcast via readlane. VALU-only: keeps the LDS pipe free.
template<int CTRL>
__device__ __forceinline__ void argmax_step(unsigned& k, int& i) {
  const unsigned tk = (unsigned)__builtin_amdgcn_update_dpp(0, (int)k, CTRL, 0xF, 0xF, true);
  const int ti = __builtin_amdgcn_update_dpp(0, i, CTRL, 0xF, 0xF, true);
  if (tk > k || (tk == k && ti < i)) { k = tk; i = ti; }
}
__device__ __forceinline__ void wave_argmax(unsigned& k, int& i) {
  argmax_step<0x111>(k, i);  // row_shr:1
  argmax_step<0x112>(k, i);  // row_shr:2
  argmax_step<0x114>(k, i);  // row_shr:4
  argmax_step<0x118>(k, i);  // row_shr:8
  argmax_step<0x142>(k, i);  // row_bcast15
  argmax_step<0x143>(k, i);  // row_bcast31
  k = (unsigned)__builtin_amdgcn_readlane((int)k, 63);
  i = __builtin_amdgcn_readlane(i, 63);
}

// Bit-exact chained row-major fp32 window sum for TWO images at once.
// im2[k] = {imgA[k], imgB[k]}; per-half adds are independent IEEE fp32 chains
// identical to the single-image version (v_pk_add_f32 or 2x v_add_f32).
template<int H, int W, int OFF>
__device__ __forceinline__ void score_ratio2(const float2* __restrict__ im2,
                                             unsigned* __restrict__ wk2,
                                             float* __restrict__ wrowA,
                                             float* __restrict__ wrowB,
                                             const int lane, const bool hasB) {
  constexpr int Wo = 14 - W + 1;
  constexpr int Ho = 14 - H + 1;
  constexpr int NWIN = Ho * Wo;
  for (int o = lane; o < NWIN; o += 64) {
    const int i = o / Wo, j = o - i * Wo;
    const float2* p = im2 + (i * 14 + j);
    float2 acc; acc.x = 0.0f; acc.y = 0.0f;
#pragma unroll
    for (int di = 0; di < H; ++di)
#pragma unroll
      for (int dj = 0; dj < W; ++dj) {
        const float2 v = p[di * 14 + dj];   // ds_read_b64: both images
        acc.x += v.x; acc.y += v.y;
      }
    const float scA = acc.x / (float)(H * W);   // IEEE fp32 div (as in R2)
    const float scB = acc.y / (float)(H * W);
    wrowA[OFF + o] = scA;
    if (hasB) wrowB[OFF + o] = scB;
    uint2 kk; kk.x = score_key(scA); kk.y = score_key(scB);
    *(uint2*)&wk2[(OFF + o) * 2] = kk;          // ds_write_b64
  }
}

__global__ __launch_bounds__(256) void appm_kernel(
    const float* __restrict__ x, const int* __restrict__ coords,
    float* __restrict__ out, int B) {

  __shared__ float4 c_box[NW];
  __shared__ float c_ar[NW];
  __shared__ float imgp[4][392];          // per wave: 196 x {imgA, imgB}
  __shared__ unsigned wkk[4][NW * 2];     // per wave: 741 x {keyA, keyB}

  const int t = threadIdx.x;
  const int wv = t >> 6;
  const int lane = t & 63;
  const int img0 = blockIdx.x * 8;
  const int imgA = img0 + wv * 2;
  const int imgB = imgA + 1;
  const bool hasA = (imgA < B);
  const bool hasB = (imgB < B);

  // ---- Phase A: coord tables (float4 box + area), shared per block ----
  for (int w = t; w < NW; w += 256) {
    const int4 c = ((const int4*)coords)[w];
    const float fx0 = (float)c.x, fy0 = (float)c.y;
    const float fx1 = (float)c.z, fy1 = (float)c.w;
    c_box[w] = make_float4(fx0, fy0, fx1, fy1);
    c_ar[w] = (fx1 - fx0 + 1.0f) * (fy1 - fy0 + 1.0f);
  }

  // ---- Phase B: stage 8 images, pair-interleaved per wave ----
  {
    int nimg = B - img0; if (nimg > 8) nimg = 8;
    const int lim = nimg * 196;
    const float* xb = x + (long long)img0 * 196;
    for (int u = t; u < lim; u += 256) {
      const int i = u / 196, k = u - i * 196;
      imgp[i >> 1][k * 2 + (i & 1)] = xb[u];
    }
  }
  __syncthreads();

  if (hasA) {
    const float2* im2 = (const float2*)imgp[wv];
    unsigned* wk2 = wkk[wv];
    float* wrowA = out + (long long)B * 12 + (long long)imgA * NW;
    float* wrowB = wrowA + NW;

    // ---- Phase C: 741 window scores for both images ----
    score_ratio2<4, 4, 0>(im2, wk2, wrowA, wrowB, lane, hasB);
    score_ratio2<3, 5, 121>(im2, wk2, wrowA, wrowB, lane, hasB);
    score_ratio2<5, 3, 241>(im2, wk2, wrowA, wrowB, lane, hasB);
    score_ratio2<6, 6, 361>(im2, wk2, wrowA, wrowB, lane, hasB);
    score_ratio2<5, 7, 442>(im2, wk2, wrowA, wrowB, lane, hasB);
    score_ratio2<7, 5, 522>(im2, wk2, wrowA, wrowB, lane, hasB);
    score_ratio2<8, 8, 602>(im2, wk2, wrowA, wrowB, lane, hasB);
    score_ratio2<6, 10, 651>(im2, wk2, wrowA, wrowB, lane, hasB);
    score_ratio2<10, 6, 696>(im2, wk2, wrowA, wrowB, lane, hasB);
    __builtin_amdgcn_wave_barrier();

    // ---- Phase D: greedy NMS for both images, 3 groups ----
    float myIA = 0.0f, mySA = 0.0f, myIB = 0.0f, mySB = 0.0f;
    int pick = 0;
    constexpr int gs_[3] = {0, 361, 602};
    constexpr int ge_[3] = {361, 602, 741};
    constexpr int gn_[3] = {3, 2, 1};
#pragma unroll
    for (int g = 0; g < 3; g++) {
      const int gs = gs_[g], ge = ge_[g];
      int lastA = gs, lastB = gs;
      float lastSA = 0.0f, lastSB = 0.0f;
#pragma unroll
      for (int n = 0; n < gn_[g]; n++) {
        unsigned bkA = 0u, bkB = 0u;
        int biA = 0, biB = 0;
        for (int o = gs + lane; o < ge; o += 64) {
          const uint2 kk = *(const uint2*)&wkk[wv][o * 2];  // ds_read_b64
          if (kk.x > bkA) { bkA = kk.x; biA = o; }
          if (kk.y > bkB) { bkB = kk.y; biB = o; }
        }
        wave_argmax(bkA, biA);
        wave_argmax(bkB, biB);

        int idxA, idxB; float scA, scB;
        if (bkA > NEG_INF_KEY) { idxA = biA; scA = key_score(bkA); }
        else { idxA = lastA; scA = lastSA; }
        if (bkB > NEG_INF_KEY) { idxB = biB; scB = key_score(bkB); }
        else { idxB = lastB; scB = lastSB; }
        lastA = idxA; lastSA = scA;
        lastB = idxB; lastSB = scB;
        if (lane == pick) { myIA = (float)idxA; mySA = scA; myIB = (float)idxB; mySB = scB; }
        pick++;

        if (n + 1 < gn_[g]) {
          // suppression: exact integer compare 4*inter > union  <=>  iou > 0.25
          const float4 bA = c_box[idxA]; const float aA = c_ar[idxA];  // broadcast
          const float4 bB = c_box[idxB]; const float aB = c_ar[idxB];
          for (int o = gs + lane; o < ge; o += 64) {
            const float4 cb = c_box[o];       // ds_read_b128
            const float ar = c_ar[o];
            const float lxA = fminf(cb.z, bA.z) - fmaxf(cb.x, bA.x) + 1.0f;
            const float lyA = fminf(cb.w, bA.w) - fmaxf(cb.y, bA.y) + 1.0f;
            const float inA = (lxA < 0.0f || lyA < 0.0f) ? 0.0f : lxA * lyA;
            const bool supA = (4.0f * inA > ar + aA - inA);
            const float lxB = fminf(cb.z, bB.z) - fmaxf(cb.x, bB.x) + 1.0f;
            const float lyB = fminf(cb.w, bB.w) - fmaxf(cb.y, bB.y) + 1.0f;
            const float inB = (lxB < 0.0f || lyB < 0.0f) ? 0.0f : lxB * lyB;
            const bool supB = (4.0f * inB > ar + aB - inB);
            uint2 kk = *(uint2*)&wkk[wv][o * 2];
            if (supA) kk.x = 0u;
            if (supB) kk.y = 0u;
            *(uint2*)&wkk[wv][o * 2] = kk;
          }
          __builtin_amdgcn_wave_barrier();
        }
      }
    }

    // ---- outputs ----
    if (lane < 6) {
      const long long a6 = (long long)imgA * 6 + lane;
      out[a6] = myIA;
      out[(long long)B * 6 + a6] = mySA;
      if (hasB) {
        const long long b6 = (long long)imgB * 6 + lane;
        out[b6] = myIB;
        out[(long long)B * 6 + b6] = mySB;
      }
    }
  }
}

extern "C" void kernel_launch(void* const* d_in, const int* in_sizes, int n_in,
                              void* d_out, int out_size, void* d_ws, size_t ws_size,
                              hipStream_t stream) {
  const float* x = (const float*)d_in[0];
  const int* coords = (const int*)d_in[1];
  float* out = (float*)d_out;
  const int B = in_sizes[0] / 196;
  const int nblk = (B + 7) / 8;
  appm_kernel<<<dim3(nblk), dim3(256), 0, stream>>>(x, coords, out, B);
}